// Round 1
// baseline (391.447 us; speedup 1.0000x reference)
//
#include <hip/hip_runtime.h>

#define NBINS 1331           // 11^3
#define NCUT  11
#define TOPK  20

// ---------------- workspace layout ----------------
// ws + 0                   : unsigned int ghist[1331]      (5324 B)
// ws + 8192                : float cut255[33]              (r,g,b scaled by 255)
// ws + 8192 + 33*4         : float cutraw[33]              (r,g,b in [0,1])
#define WS_HIST_OFF   0
#define WS_CUT255_OFF 8192
#define WS_CUTRAW_OFF (8192 + 33 * 4)

__global__ void prep_kernel(const float* __restrict__ r_cut,
                            const float* __restrict__ g_cut,
                            const float* __restrict__ b_cut,
                            float* __restrict__ cut255,
                            float* __restrict__ cutraw) {
    int t = threadIdx.x;
    if (t < 3) {
        const float* src = (t == 0) ? r_cut : ((t == 1) ? g_cut : b_cut);
        float s[NCUT];
        for (int i = 0; i < NCUT; ++i) s[i] = src[i];
        // insertion sort ascending
        for (int i = 1; i < NCUT; ++i) {
            float v = s[i];
            int j = i - 1;
            while (j >= 0 && s[j] > v) { s[j + 1] = s[j]; --j; }
            s[j + 1] = v;
        }
        // clip to [0,1], then pin endpoints (reference order)
        for (int i = 0; i < NCUT; ++i) s[i] = fminf(fmaxf(s[i], 0.0f), 1.0f);
        s[0] = 0.0f;
        s[NCUT - 1] = 1.0f;
        for (int i = 0; i < NCUT; ++i) {
            cutraw[t * NCUT + i] = s[i];
            cut255[t * NCUT + i] = s[i] * 255.0f;   // same fp32 mul as JAX rc*255
        }
    }
}

__global__ __launch_bounds__(256) void hist_kernel(const float4* __restrict__ x,
                                                   const float* __restrict__ cut255,
                                                   unsigned int* __restrict__ ghist,
                                                   int npix) {
    __shared__ unsigned int sh[NBINS];
    for (int i = threadIdx.x; i < NBINS; i += blockDim.x) sh[i] = 0;

    // cuts -> registers (uniform addresses -> scalar loads)
    float cr[NCUT], cg[NCUT], cb[NCUT];
#pragma unroll
    for (int j = 0; j < NCUT; ++j) {
        cr[j] = cut255[j];
        cg[j] = cut255[NCUT + j];
        cb[j] = cut255[2 * NCUT + j];
    }
    __syncthreads();

    int stride = gridDim.x * blockDim.x;
    for (int i = blockIdx.x * blockDim.x + threadIdx.x; i < npix; i += stride) {
        float4 v = x[i];
        int r = 0, g = 0, b = 0;
#pragma unroll
        for (int j = 0; j < NCUT; ++j) {
            r += (cr[j] < v.x);
            g += (cg[j] < v.y);
            b += (cb[j] < v.z);
        }
        // python (iv-1) % 11 : iv in [0,10] here (v < 255 <= cut[10]*? guarded by select anyway)
        r = r ? (r - 1) : (NCUT - 1);
        g = g ? (g - 1) : (NCUT - 1);
        b = b ? (b - 1) : (NCUT - 1);
        atomicAdd(&sh[r * 121 + g * 11 + b], 1u);
    }
    __syncthreads();
    for (int i = threadIdx.x; i < NBINS; i += blockDim.x) {
        unsigned int c = sh[i];
        if (c) atomicAdd(&ghist[i], c);
    }
}

__global__ __launch_bounds__(256) void topk_kernel(const unsigned int* __restrict__ ghist,
                                                   const float* __restrict__ cutraw,
                                                   float* __restrict__ out) {
    __shared__ unsigned long long key[NBINS];
    __shared__ unsigned long long red[256];
    __shared__ int topbin[TOPK];
    int t = threadIdx.x;

    // key: higher count wins; tie -> lower bin index wins (argsort stable)
    for (int i = t; i < NBINS; i += 256)
        key[i] = ((unsigned long long)ghist[i] << 11) |
                 (unsigned long long)(2047 - i);
    __syncthreads();

    for (int it = 0; it < TOPK; ++it) {
        unsigned long long m = 0ull;
        for (int i = t; i < NBINS; i += 256) {
            unsigned long long k = key[i];
            m = (k > m) ? k : m;
        }
        red[t] = m;
        __syncthreads();
        for (int s = 128; s > 0; s >>= 1) {
            if (t < s) {
                unsigned long long a = red[t], b2 = red[t + s];
                red[t] = (b2 > a) ? b2 : a;
            }
            __syncthreads();
        }
        if (t == 0) {
            int bin = 2047 - (int)(red[0] & 2047ull);
            topbin[it] = bin;
            key[bin] = 0ull;          // remove winner
        }
        __syncthreads();
    }

    if (t < TOPK) {
        int bin = topbin[t];
        int tr = (bin / 121) % NCUT;
        int tg = (bin / 11) % NCUT;
        int tb = bin % NCUT;
        int r = min(tr, NCUT - 2);
        int g = min(tg, NCUT - 2);
        int b = min(tb, NCUT - 2);
        const float* rc = cutraw;
        const float* gc = cutraw + NCUT;
        const float* bc = cutraw + 2 * NCUT;
        float4 o;
        o.x = 255.0f * (float)r / 11.0f + (rc[r + 1] - rc[r]) * 255.0f / 2.0f;
        o.y = 255.0f * (float)g / 11.0f + (gc[g + 1] - gc[g]) * 255.0f / 2.0f;
        o.z = 255.0f * (float)b / 11.0f + (bc[b + 1] - bc[b]) * 255.0f / 2.0f;
        o.w = 255.0f;
        reinterpret_cast<float4*>(out)[t] = o;
    }
}

extern "C" void kernel_launch(void* const* d_in, const int* in_sizes, int n_in,
                              void* d_out, int out_size, void* d_ws, size_t ws_size,
                              hipStream_t stream) {
    const float* x     = (const float*)d_in[0];
    const float* r_cut = (const float*)d_in[1];
    const float* g_cut = (const float*)d_in[2];
    const float* b_cut = (const float*)d_in[3];
    float* out = (float*)d_out;

    int npix = in_sizes[0] / 4;

    unsigned int* ghist = (unsigned int*)((char*)d_ws + WS_HIST_OFF);
    float* cut255       = (float*)((char*)d_ws + WS_CUT255_OFF);
    float* cutraw       = (float*)((char*)d_ws + WS_CUTRAW_OFF);

    // ws is poisoned 0xAA before every launch: zero the histogram each call.
    hipMemsetAsync(ghist, 0, NBINS * sizeof(unsigned int), stream);

    prep_kernel<<<1, 64, 0, stream>>>(r_cut, g_cut, b_cut, cut255, cutraw);

    hist_kernel<<<1024, 256, 0, stream>>>((const float4*)x, cut255, ghist, npix);

    topk_kernel<<<1, 256, 0, stream>>>(ghist, cutraw, out);
}